// Round 2
// baseline (14057.445 us; speedup 1.0000x reference)
//
#include <hip/hip_runtime.h>
#include <stdint.h>

// Problem constants
#define TSTEPS 300
#define BATCH  1024
#define MB     16            // batch rows per workgroup
#define NWG    (BATCH / MB)  // 64 workgroups
#define FRAGS_L0 36          // 9 ksteps * 4 gate tiles (K = 32(x) + 256(h0))
#define FRAGS_L1 64          // 16 ksteps * 4 gate tiles (K = 256(h0new) + 256(h1))
#define FRAGS_PW (FRAGS_L0 + FRAGS_L1)  // 100 frags per wave per step

typedef __bf16 bf16x8 __attribute__((ext_vector_type(8)));
typedef float  f32x4  __attribute__((ext_vector_type(4)));

__device__ __forceinline__ uint16_t f2bf(float f) {
  uint32_t u = __builtin_bit_cast(uint32_t, f);
  u += 0x7fffu + ((u >> 16) & 1u);   // RNE
  return (uint16_t)(u >> 16);
}
__device__ __forceinline__ float bf2f(uint16_t h) {
  uint32_t u = ((uint32_t)h) << 16;
  return __builtin_bit_cast(float, u);
}
__device__ __forceinline__ float sigm(float x) { return 1.0f / (1.0f + __expf(-x)); }
__device__ __forceinline__ float tanh_(float x) {
  float e = __expf(2.0f * x);
  return (e - 1.0f) / (e + 1.0f);
}

// ---------------------------------------------------------------------------
// P1: embedding gather + reshape(300,B,25) packed into MFMA A-frag layout:
// Xf[((t*64+wg)*64+lane)*8 + jj]  (bf16); lane: m=lane&15, k=(lane>>4)*8+jj
// ---------------------------------------------------------------------------
__global__ void gather_x(const int* __restrict__ tok, const float* __restrict__ emb,
                         uint16_t* __restrict__ Xf) {
  int idx = blockIdx.x * 256 + threadIdx.x;       // < 300*64*512 = 9,830,400
  int t    = idx >> 15;
  int rem  = idx & 32767;
  int wg   = rem >> 9;
  int e512 = rem & 511;
  int lane = e512 >> 3;
  int jj   = e512 & 7;
  int m = lane & 15, quad = lane >> 4;
  int k = quad * 8 + jj;
  float v = 0.0f;
  if (k < 25) {
    int b = wg * 16 + m;
    int n = (t * 1024 + b) * 25 + k;              // flat index in [300,1024,25]
    int s  = n / 307200;                          // 1024*300
    int r2 = n - s * 307200;
    int bb = r2 / 300;
    int e  = r2 - bb * 300;
    int token = tok[bb * 25 + s];                 // input[bb][s]
    v = emb[(size_t)token * 300 + e];
  }
  Xf[idx] = f2bf(v);
}

// ---------------------------------------------------------------------------
// P2: pack all weights (bf16) into per-wave MFMA B-frag streams.
// Wp[((w*100+frag)*64+lane)*8 + jj]; lane: n=lane&15, k=(lane>>4)*8+jj.
// ---------------------------------------------------------------------------
__global__ void pack_w(const float* __restrict__ Wih0, const float* __restrict__ Whh0,
                       const float* __restrict__ Wih1, const float* __restrict__ Whh1,
                       uint16_t* __restrict__ Wp) {
  int idx = blockIdx.x * 256 + threadIdx.x;       // < 16*100*512 = 819,200
  int w   = idx / 51200;
  int rem = idx - w * 51200;
  int frag = rem >> 9;
  int e    = rem & 511;
  int lane = e >> 3, jj = e & 7;
  int nl = lane & 15, quad = lane >> 4;
  int kk = quad * 8 + jj;
  float v;
  if (frag < FRAGS_L0) {
    int ks = frag >> 2, nt = frag & 3;
    int n = nt * 256 + w * 16 + nl;
    if (ks == 0) v = (kk < 25) ? Wih0[n * 25 + kk] : 0.0f;
    else         v = Whh0[n * 256 + (ks - 1) * 32 + kk];
  } else {
    int f1 = frag - FRAGS_L0;
    int ks = f1 >> 2, nt = f1 & 3;
    int n = nt * 256 + w * 16 + nl;
    int k = ks * 32 + kk;
    v = (k < 256) ? Wih1[n * 256 + k] : Whh1[n * 256 + (k - 256)];
  }
  Wp[idx] = f2bf(v);
}

// ---------------------------------------------------------------------------
// Main persistent kernel. 64 blocks x 1024 threads (16 waves), block = 16
// batch rows x 300 steps. Wave w owns gate cols w*16..w*16+15 (4 gate tiles).
// Weight stream (100 frags/wave/step, step-invariant addresses) is consumed
// through an explicit 3-group (12-frag, 48-VGPR) software pipeline whose
// prefetch flows across the phase barrier AND across steps. t is unrolled by
// 3 so the slot rotation (group % 3, 75 groups per macro-step) is static.
// ---------------------------------------------------------------------------
__global__ __launch_bounds__(1024, 4) void lstm_main(
    const float* __restrict__ h0in, const float* __restrict__ c0in,
    const float* __restrict__ fcw,  const float* __restrict__ fcb,
    const float* __restrict__ decw, const float* __restrict__ decb,
    const float* __restrict__ bih0, const float* __restrict__ bhh0,
    const float* __restrict__ bih1, const float* __restrict__ bhh1,
    const uint16_t* __restrict__ Xf, const uint16_t* __restrict__ Wp,
    float* __restrict__ out) {
  __shared__ uint16_t h0s[2][16][264];
  __shared__ uint16_t h1s[2][16][264];
  __shared__ float fcs[16][10];

  const int wg   = blockIdx.x;
  const int tid  = threadIdx.x;
  const int w    = tid >> 6;
  const int lane = tid & 63;
  const int jl   = lane & 15;
  const int quad = lane >> 4;
  const int jcol = w * 16 + jl;

  for (int idx = tid; idx < 16 * 256; idx += 1024) {
    int r = idx >> 8, k = idx & 255;
    int b = wg * 16 + r;
    h0s[0][r][k] = f2bf(h0in[(size_t)b * 256 + k]);
    h1s[0][r][k] = f2bf(h0in[262144 + (size_t)b * 256 + k]);
  }
  float c0r[4], c1r[4], h0v[4], h1v[4];
#pragma unroll
  for (int r = 0; r < 4; r++) {
    size_t b = wg * 16 + quad * 4 + r;
    c0r[r] = c0in[b * 256 + jcol];
    c1r[r] = c0in[262144 + b * 256 + jcol];
  }
  float bias0[4], bias1[4];
#pragma unroll
  for (int nt = 0; nt < 4; nt++) {
    int n = nt * 256 + jcol;
    bias0[nt] = bih0[n] + bhh0[n];
    bias1[nt] = bih1[n] + bhh1[n];
  }
  __syncthreads();

  const uint4* pw = (const uint4*)Wp + (size_t)(w * FRAGS_PW) * 64 + lane;
  const uint4* px = (const uint4*)Xf;

  // ---- prime the 3-group pipeline (frags 0..11) + first x frag ----
  bf16x8 bq[3][4];
#pragma unroll
  for (int s = 0; s < 3; s++)
#pragma unroll
    for (int nt = 0; nt < 4; nt++)
      bq[s][nt] = __builtin_bit_cast(bf16x8, pw[(s * 4 + nt) * 64]);
  bf16x8 xfrag = __builtin_bit_cast(bf16x8, px[(size_t)(0 * 64 + wg) * 64 + lane]);
  bf16x8 xnext;

  int p = 0;
  for (int tm = 0; tm < TSTEPS / 3; tm++) {
#pragma unroll
    for (int sub = 0; sub < 3; sub++) {
      const int t  = tm * 3 + sub;
      const int gb = sub * 25;              // static group base within macro-step

      // ---------------- layer 0 ----------------
      f32x4 acc[4];
#pragma unroll
      for (int nt = 0; nt < 4; nt++)
        acc[nt] = (f32x4){bias0[nt], bias0[nt], bias0[nt], bias0[nt]};

      bf16x8 afrag = xfrag;
#pragma unroll
      for (int ks = 0; ks < 9; ks++) {
        const int slot = (gb + ks) % 3;
        bf16x8 anext = afrag;
        if (ks < 8)
          anext = __builtin_bit_cast(bf16x8,
                    *(const uint4*)&h0s[p][jl][ks * 32 + quad * 8]);
#pragma unroll
        for (int nt = 0; nt < 4; nt++)
          acc[nt] = __builtin_amdgcn_mfma_f32_16x16x32_bf16(afrag, bq[slot][nt], acc[nt], 0, 0, 0);
        // prefetch group gb+ks+3 (wraps mod 25 into this/next step's stream)
        {
          const int fo = ((gb + ks + 3) % 25) * 4;
#pragma unroll
          for (int nt = 0; nt < 4; nt++)
            bq[slot][nt] = __builtin_bit_cast(bf16x8, pw[(fo + nt) * 64]);
        }
        afrag = anext;
      }
#pragma unroll
      for (int r = 0; r < 4; r++) {
        float gi = sigm(acc[0][r]);
        float gf = sigm(acc[1][r]);
        float gg = tanh_(acc[2][r]);
        float go = sigm(acc[3][r]);
        float c = gf * c0r[r] + gi * gg;
        c0r[r] = c;
        float h = go * tanh_(c);
        h0v[r] = h;
        h0s[1 - p][quad * 4 + r][jcol] = f2bf(h);
      }
      __syncthreads();   // h0_new visible

      // ---------------- layer 1 ----------------
#pragma unroll
      for (int nt = 0; nt < 4; nt++)
        acc[nt] = (f32x4){bias1[nt], bias1[nt], bias1[nt], bias1[nt]};

      afrag = __builtin_bit_cast(bf16x8, *(const uint4*)&h0s[1 - p][jl][quad * 8]);
#pragma unroll
      for (int ks = 0; ks < 16; ks++) {
        const int slot = (gb + 9 + ks) % 3;
        if (ks == 0) {          // prefetch next step's x frag (clamped)
          int tn = (t + 1 < TSTEPS) ? t + 1 : 0;
          xnext = __builtin_bit_cast(bf16x8, px[(size_t)(tn * 64 + wg) * 64 + lane]);
        }
        bf16x8 anext = afrag;
        if (ks < 15) {
          const int ksn = ks + 1;
          const uint16_t* abase = (ksn < 8)
              ? &h0s[1 - p][jl][ksn * 32 + quad * 8]
              : &h1s[p][jl][(ksn - 8) * 32 + quad * 8];
          anext = __builtin_bit_cast(bf16x8, *(const uint4*)abase);
        }
#pragma unroll
        for (int nt = 0; nt < 4; nt++)
          acc[nt] = __builtin_amdgcn_mfma_f32_16x16x32_bf16(afrag, bq[slot][nt], acc[nt], 0, 0, 0);
        {
          const int fo = ((gb + 9 + ks + 3) % 25) * 4;
#pragma unroll
          for (int nt = 0; nt < 4; nt++)
            bq[slot][nt] = __builtin_bit_cast(bf16x8, pw[(fo + nt) * 64]);
        }
        afrag = anext;
      }
#pragma unroll
      for (int r = 0; r < 4; r++) {
        float gi = sigm(acc[0][r]);
        float gf = sigm(acc[1][r]);
        float gg = tanh_(acc[2][r]);
        float go = sigm(acc[3][r]);
        float c = gf * c1r[r] + gi * gg;
        c1r[r] = c;
        float h = go * tanh_(c);
        h1v[r] = h;
        h1s[1 - p][quad * 4 + r][jcol] = f2bf(h);
      }
      __syncthreads();
      p ^= 1;
      xfrag = xnext;
    }
  }

  // ---------------- epilogue ----------------
  float* outH = out + 2048;
  float* outC = out + 2048 + 524288;
#pragma unroll
  for (int r = 0; r < 4; r++) {
    size_t b = wg * 16 + quad * 4 + r;
    outH[b * 256 + jcol]          = h0v[r];
    outH[262144 + b * 256 + jcol] = h1v[r];
    outC[b * 256 + jcol]          = c0r[r];
    outC[262144 + b * 256 + jcol] = c1r[r];
  }
  if (tid < 160) {
    int r = tid / 10, ju = tid - r * 10;
    float s = fcb[ju];
    for (int k = 0; k < 256; k++)
      s += bf2f(h1s[p][r][k]) * fcw[ju * 256 + k];
    fcs[r][ju] = fmaxf(s, 0.0f);
  }
  __syncthreads();
  if (tid < 32) {
    int r = tid & 15, m = tid >> 4;
    float d = decb[m];
#pragma unroll
    for (int q = 0; q < 10; q++) d += fcs[r][q] * decw[m * 10 + q];
    out[(size_t)m * 1024 + wg * 16 + r] = d;
  }
}

// ---------------------------------------------------------------------------
extern "C" void kernel_launch(void* const* d_in, const int* in_sizes, int n_in,
                              void* d_out, int out_size, void* d_ws, size_t ws_size,
                              hipStream_t stream) {
  const int*   tok  = (const int*)d_in[0];
  const float* h0   = (const float*)d_in[1];
  const float* c0   = (const float*)d_in[2];
  const float* emb  = (const float*)d_in[3];
  const float* fcw  = (const float*)d_in[4];
  const float* fcb  = (const float*)d_in[5];
  const float* decw = (const float*)d_in[6];
  const float* decb = (const float*)d_in[7];
  const float* Wih0 = (const float*)d_in[8];
  const float* Whh0 = (const float*)d_in[9];
  const float* bih0 = (const float*)d_in[10];
  const float* bhh0 = (const float*)d_in[11];
  const float* Wih1 = (const float*)d_in[12];
  const float* Whh1 = (const float*)d_in[13];
  const float* bih1 = (const float*)d_in[14];
  const float* bhh1 = (const float*)d_in[15];

  uint16_t* Xf  = (uint16_t*)d_ws;       // 9,830,400 bf16 = 19.66 MB
  uint16_t* Wpk = Xf + 9830400;          //   819,200 bf16 =  1.64 MB

  gather_x<<<38400, 256, 0, stream>>>(tok, emb, Xf);
  pack_w<<<3200, 256, 0, stream>>>(Wih0, Whh0, Wih1, Whh1, Wpk);
  lstm_main<<<NWG, 1024, 0, stream>>>(h0, c0, fcw, fcb, decw, decb,
                                      bih0, bhh0, bih1, bhh1, Xf, Wpk,
                                      (float*)d_out);
}

// Round 3
// 13359.351 us; speedup vs baseline: 1.0523x; 1.0523x over previous
//
#include <hip/hip_runtime.h>
#include <stdint.h>

// Problem constants
#define TSTEPS 300
#define BATCH  1024
#define MB     16            // batch rows per workgroup
#define NWG    (BATCH / MB)  // 64 workgroups
#define FRAGS_L0 36          // 9 ksteps * 4 gate tiles (K = 32(x) + 256(h0))
#define FRAGS_L1 64          // 16 ksteps * 4 gate tiles (K = 256(h0new) + 256(h1))
#define FRAGS_PW (FRAGS_L0 + FRAGS_L1)  // 100 frags per wave (step-invariant!)

typedef __bf16 bf16x8 __attribute__((ext_vector_type(8)));
typedef float  f32x4  __attribute__((ext_vector_type(4)));

__device__ __forceinline__ uint16_t f2bf(float f) {
  uint32_t u = __builtin_bit_cast(uint32_t, f);
  u += 0x7fffu + ((u >> 16) & 1u);   // RNE
  return (uint16_t)(u >> 16);
}
__device__ __forceinline__ float bf2f(uint16_t h) {
  uint32_t u = ((uint32_t)h) << 16;
  return __builtin_bit_cast(float, u);
}
__device__ __forceinline__ float sigm(float x) { return 1.0f / (1.0f + __expf(-x)); }
__device__ __forceinline__ float tanh_(float x) {
  float e = __expf(2.0f * x);
  return (e - 1.0f) / (e + 1.0f);
}

// ---------------------------------------------------------------------------
// P1: embedding gather + reshape(300,B,25) packed into MFMA A-frag layout:
// Xf[((t*64+wg)*64+lane)*8 + jj]  (bf16); lane: m=lane&15, k=(lane>>4)*8+jj
// ---------------------------------------------------------------------------
__global__ void gather_x(const int* __restrict__ tok, const float* __restrict__ emb,
                         uint16_t* __restrict__ Xf) {
  int idx = blockIdx.x * 256 + threadIdx.x;       // < 300*64*512 = 9,830,400
  int t    = idx >> 15;
  int rem  = idx & 32767;
  int wg   = rem >> 9;
  int e512 = rem & 511;
  int lane = e512 >> 3;
  int jj   = e512 & 7;
  int m = lane & 15, quad = lane >> 4;
  int k = quad * 8 + jj;
  float v = 0.0f;
  if (k < 25) {
    int b = wg * 16 + m;
    int n = (t * 1024 + b) * 25 + k;              // flat index in [300,1024,25]
    int s  = n / 307200;                          // 1024*300
    int r2 = n - s * 307200;
    int bb = r2 / 300;
    int e  = r2 - bb * 300;
    int token = tok[bb * 25 + s];                 // input[bb][s]
    v = emb[(size_t)token * 300 + e];
  }
  Xf[idx] = f2bf(v);
}

// ---------------------------------------------------------------------------
// P2: pack all weights (bf16) into per-wave MFMA B-frag streams.
// Wp[((w*100+frag)*64+lane)*8 + jj]; lane: n=lane&15, k=(lane>>4)*8+jj.
// ---------------------------------------------------------------------------
__global__ void pack_w(const float* __restrict__ Wih0, const float* __restrict__ Whh0,
                       const float* __restrict__ Wih1, const float* __restrict__ Whh1,
                       uint16_t* __restrict__ Wp) {
  int idx = blockIdx.x * 256 + threadIdx.x;       // < 16*100*512 = 819,200
  int w   = idx / 51200;
  int rem = idx - w * 51200;
  int frag = rem >> 9;
  int e    = rem & 511;
  int lane = e >> 3, jj = e & 7;
  int nl = lane & 15, quad = lane >> 4;
  int kk = quad * 8 + jj;
  float v;
  if (frag < FRAGS_L0) {
    int ks = frag >> 2, nt = frag & 3;
    int n = nt * 256 + w * 16 + nl;
    if (ks == 0) v = (kk < 25) ? Wih0[n * 25 + kk] : 0.0f;
    else         v = Whh0[n * 256 + (ks - 1) * 32 + kk];
  } else {
    int f1 = frag - FRAGS_L0;
    int ks = f1 >> 2, nt = f1 & 3;
    int n = nt * 256 + w * 16 + nl;
    int k = ks * 32 + kk;
    v = (k < 256) ? Wih1[n * 256 + k] : Whh1[n * 256 + (k - 256)];
  }
  Wp[idx] = f2bf(v);
}

// ---------------------------------------------------------------------------
// Main persistent kernel. 64 blocks x 1024 threads (16 waves), block = 16
// batch rows x 300 steps. Wave w owns gate cols w*16..w*16+15 (4 gate tiles).
// ALL weights live in registers: 100 frags x 4 VGPR = 400 VGPR/wave, loaded
// once in the prologue (budget: 512/wave at 4 waves/SIMD, unified VGPR+AGPR).
// Per-step global traffic = one 1KB x-frag per wave. 2 barriers/step.
// ---------------------------------------------------------------------------
__global__ __launch_bounds__(1024, 4) void lstm_main(
    const float* __restrict__ h0in, const float* __restrict__ c0in,
    const float* __restrict__ fcw,  const float* __restrict__ fcb,
    const float* __restrict__ decw, const float* __restrict__ decb,
    const float* __restrict__ bih0, const float* __restrict__ bhh0,
    const float* __restrict__ bih1, const float* __restrict__ bhh1,
    const uint16_t* __restrict__ Xf, const uint16_t* __restrict__ Wp,
    float* __restrict__ out) {
  __shared__ uint16_t h0s[2][16][264];
  __shared__ uint16_t h1s[2][16][264];
  __shared__ float fcs[16][10];

  const int wg   = blockIdx.x;
  const int tid  = threadIdx.x;
  const int w    = tid >> 6;
  const int lane = tid & 63;
  const int jl   = lane & 15;
  const int quad = lane >> 4;
  const int jcol = w * 16 + jl;

  for (int idx = tid; idx < 16 * 256; idx += 1024) {
    int r = idx >> 8, k = idx & 255;
    int b = wg * 16 + r;
    h0s[0][r][k] = f2bf(h0in[(size_t)b * 256 + k]);
    h1s[0][r][k] = f2bf(h0in[262144 + (size_t)b * 256 + k]);
  }
  float c0r[4], c1r[4];
#pragma unroll
  for (int r = 0; r < 4; r++) {
    size_t b = wg * 16 + quad * 4 + r;
    c0r[r] = c0in[b * 256 + jcol];
    c1r[r] = c0in[262144 + b * 256 + jcol];
  }
  float bias0[4], bias1[4];
#pragma unroll
  for (int nt = 0; nt < 4; nt++) {
    int n = nt * 256 + jcol;
    bias0[nt] = bih0[n] + bhh0[n];
    bias1[nt] = bih1[n] + bhh1[n];
  }

  // ---- load ALL weight frags into registers (step-invariant) ----
  const uint4* pw = (const uint4*)Wp + (size_t)(w * FRAGS_PW) * 64 + lane;
  bf16x8 wreg[FRAGS_PW];
#pragma unroll
  for (int f = 0; f < FRAGS_PW; f++)
    wreg[f] = __builtin_bit_cast(bf16x8, pw[f * 64]);

  const uint4* px = (const uint4*)Xf;
  bf16x8 xfrag = __builtin_bit_cast(bf16x8, px[(size_t)(0 * 64 + wg) * 64 + lane]);
  bf16x8 xnext;

  float* outH = out + 2048;
  float* outC = out + 2048 + 524288;

  __syncthreads();

  int p = 0;
  for (int t = 0; t < TSTEPS; t++) {
    // ---------------- layer 0: gates = x_t @ Wih0^T + h0 @ Whh0^T + b ------
    f32x4 acc[4];
#pragma unroll
    for (int nt = 0; nt < 4; nt++)
      acc[nt] = (f32x4){bias0[nt], bias0[nt], bias0[nt], bias0[nt]};

    bf16x8 afrag = xfrag;
#pragma unroll
    for (int ks = 0; ks < 9; ks++) {
      bf16x8 anext = afrag;
      if (ks < 8)
        anext = __builtin_bit_cast(bf16x8,
                  *(const uint4*)&h0s[p][jl][ks * 32 + quad * 8]);
#pragma unroll
      for (int nt = 0; nt < 4; nt++)
        acc[nt] = __builtin_amdgcn_mfma_f32_16x16x32_bf16(afrag, wreg[ks * 4 + nt], acc[nt], 0, 0, 0);
      afrag = anext;
    }
#pragma unroll
    for (int r = 0; r < 4; r++) {
      float gi = sigm(acc[0][r]);
      float gf = sigm(acc[1][r]);
      float gg = tanh_(acc[2][r]);
      float go = sigm(acc[3][r]);
      float c = gf * c0r[r] + gi * gg;
      c0r[r] = c;
      float h = go * tanh_(c);
      h0s[1 - p][quad * 4 + r][jcol] = f2bf(h);
      if (t == TSTEPS - 1) {
        size_t b = wg * 16 + quad * 4 + r;
        outH[b * 256 + jcol] = h;
        outC[b * 256 + jcol] = c;
      }
    }
    __syncthreads();   // h0_new visible

    // ---------------- layer 1: gates = h0_new @ Wih1^T + h1 @ Whh1^T + b ---
#pragma unroll
    for (int nt = 0; nt < 4; nt++)
      acc[nt] = (f32x4){bias1[nt], bias1[nt], bias1[nt], bias1[nt]};

    afrag = __builtin_bit_cast(bf16x8, *(const uint4*)&h0s[1 - p][jl][quad * 8]);
#pragma unroll
    for (int ks = 0; ks < 16; ks++) {
      if (ks == 0) {          // prefetch next step's x frag (clamped)
        int tn = (t + 1 < TSTEPS) ? t + 1 : 0;
        xnext = __builtin_bit_cast(bf16x8, px[(size_t)(tn * 64 + wg) * 64 + lane]);
      }
      bf16x8 anext = afrag;
      if (ks < 15) {
        const int ksn = ks + 1;
        const uint16_t* abase = (ksn < 8)
            ? &h0s[1 - p][jl][ksn * 32 + quad * 8]
            : &h1s[p][jl][(ksn - 8) * 32 + quad * 8];
        anext = __builtin_bit_cast(bf16x8, *(const uint4*)abase);
      }
#pragma unroll
      for (int nt = 0; nt < 4; nt++)
        acc[nt] = __builtin_amdgcn_mfma_f32_16x16x32_bf16(afrag, wreg[FRAGS_L0 + ks * 4 + nt], acc[nt], 0, 0, 0);
      afrag = anext;
    }
#pragma unroll
    for (int r = 0; r < 4; r++) {
      float gi = sigm(acc[0][r]);
      float gf = sigm(acc[1][r]);
      float gg = tanh_(acc[2][r]);
      float go = sigm(acc[3][r]);
      float c = gf * c1r[r] + gi * gg;
      c1r[r] = c;
      float h = go * tanh_(c);
      h1s[1 - p][quad * 4 + r][jcol] = f2bf(h);
      if (t == TSTEPS - 1) {
        size_t b = wg * 16 + quad * 4 + r;
        outH[262144 + b * 256 + jcol] = h;
        outC[262144 + b * 256 + jcol] = c;
      }
    }
    __syncthreads();
    p ^= 1;
    xfrag = xnext;
  }

  // ---------------- epilogue: fc + decoder ----------------
  if (tid < 160) {
    int r = tid / 10, ju = tid - r * 10;
    float s = fcb[ju];
    for (int k = 0; k < 256; k++)
      s += bf2f(h1s[p][r][k]) * fcw[ju * 256 + k];
    fcs[r][ju] = fmaxf(s, 0.0f);
  }
  __syncthreads();
  if (tid < 32) {
    int r = tid & 15, m = tid >> 4;
    float d = decb[m];
#pragma unroll
    for (int q = 0; q < 10; q++) d += fcs[r][q] * decw[m * 10 + q];
    out[(size_t)m * 1024 + wg * 16 + r] = d;
  }
}

// ---------------------------------------------------------------------------
extern "C" void kernel_launch(void* const* d_in, const int* in_sizes, int n_in,
                              void* d_out, int out_size, void* d_ws, size_t ws_size,
                              hipStream_t stream) {
  const int*   tok  = (const int*)d_in[0];
  const float* h0   = (const float*)d_in[1];
  const float* c0   = (const float*)d_in[2];
  const float* emb  = (const float*)d_in[3];
  const float* fcw  = (const float*)d_in[4];
  const float* fcb  = (const float*)d_in[5];
  const float* decw = (const float*)d_in[6];
  const float* decb = (const float*)d_in[7];
  const float* Wih0 = (const float*)d_in[8];
  const float* Whh0 = (const float*)d_in[9];
  const float* bih0 = (const float*)d_in[10];
  const float* bhh0 = (const float*)d_in[11];
  const float* Wih1 = (const float*)d_in[12];
  const float* Whh1 = (const float*)d_in[13];
  const float* bih1 = (const float*)d_in[14];
  const float* bhh1 = (const float*)d_in[15];

  uint16_t* Xf  = (uint16_t*)d_ws;       // 9,830,400 bf16 = 19.66 MB
  uint16_t* Wpk = Xf + 9830400;          //   819,200 bf16 =  1.64 MB

  gather_x<<<38400, 256, 0, stream>>>(tok, emb, Xf);
  pack_w<<<3200, 256, 0, stream>>>(Wih0, Whh0, Wih1, Whh1, Wpk);
  lstm_main<<<NWG, 1024, 0, stream>>>(h0, c0, fcw, fcb, decw, decb,
                                      bih0, bhh0, bih1, bhh1, Xf, Wpk,
                                      (float*)d_out);
}